// Round 10
// baseline (322.280 us; speedup 1.0000x reference)
//
#include <hip/hip_runtime.h>
#include <hip/hip_fp16.h>
#include <stdint.h>

// ============================================================================
// Mix_Loss on MI355X.  R10 (from passing R9 @232.5us):
//  - k_sample fast-math: gumbel logf->__logf, logit d^2/dn -> __fdividef,
//    sum(log dn) -> __logf of two 16-element products (dn in [0.02,2.05]).
//  - k_flags vectorized: 4 px/thread uint2 loads, per-quarter counts (layout
//    identical to scan/place expectations).
//  - 8 -> 5 launches: scan = block 512 of k_pq; protoFinal = last k_proto
//    block (ticket + __hip_atomic_load); final = last k_sample block.
// ============================================================================

#define NPIX  262144   // B*H*W = 4*256*256
#define NCLS  8
#define NQ    256
#define NNEG  256
#define NBLK  1024     // 256-pixel chunks for scan/place

typedef unsigned short u16;
typedef unsigned int   u32;

struct TFKeys { u32 k1[8][2], k2[8][2], k3[8][2]; };

// JAX threefry2x32 (20 rounds)
__host__ __device__ inline void tf2x32(u32 k0, u32 k1, u32 x0, u32 x1, u32& o0, u32& o1) {
  u32 ks2 = k0 ^ k1 ^ 0x1BD11BDAu;
  x0 += k0; x1 += k1;
#define TFR(R) { x0 += x1; x1 = (x1 << (R)) | (x1 >> (32 - (R))); x1 ^= x0; }
  TFR(13) TFR(15) TFR(26) TFR(6)
  x0 += k1;  x1 += ks2 + 1u;
  TFR(17) TFR(29) TFR(16) TFR(24)
  x0 += ks2; x1 += k0 + 2u;
  TFR(13) TFR(15) TFR(26) TFR(6)
  x0 += k0;  x1 += k1 + 3u;
  TFR(17) TFR(29) TFR(16) TFR(24)
  x0 += k1;  x1 += ks2 + 4u;
  TFR(13) TFR(15) TFR(26) TFR(6)
  x0 += ks2; x1 += k0 + 5u;
#undef TFR
  o0 = x0; o1 = x1;
}

__device__ inline float bfv(u16 v) { return __uint_as_float(((u32)v) << 16); }
__device__ inline float lo16(u32 v) { return __uint_as_float(v << 16); }
__device__ inline float hi16(u32 v) { return __uint_as_float(v & 0xFFFF0000u); }
__device__ inline float u01(u32 bits) { return __uint_as_float((bits >> 9) | 0x3F800000u) - 1.0f; }
__device__ inline u32 rbits(u32 k0, u32 k1, u32 idx) { u32 a, b; tf2x32(k0, k1, 0u, idx, a, b); return a ^ b; }
__device__ inline u32 packPQ(float p, float q) {
  return (u32)__half_as_ushort(__float2half(p)) | ((u32)__half_as_ushort(__float2half(q)) << 16);
}
__device__ inline float2 unpackPQ(u32 v) {
  return make_float2(__half2float(__ushort_as_half((u16)(v & 0xFFFFu))),
                     __half2float(__ushort_as_half((u16)(v >> 16))));
}
__device__ inline float aload(const float* p) {
  return __hip_atomic_load(p, __ATOMIC_RELAXED, __HIP_MEMORY_SCOPE_AGENT);
}

// ---------------------------------------------------------------------------
// R10 k_flags: 4 px/thread, uint2 loads; per-quarter counts keep blockCnt
// layout [16][1024] with 256-px granularity. Block 0 inits accumulators.
__global__ __launch_bounds__(256) void k_flags(const u16* __restrict__ lab, const u16* __restrict__ msk,
                                               const u16* __restrict__ prb, unsigned char* __restrict__ flags,
                                               int* __restrict__ blockCnt,
                                               float* __restrict__ protoAcc, float* __restrict__ ceAcc,
                                               int* __restrict__ diag, int* __restrict__ syncCtr) {
  __shared__ int cnt[4][16];
  int t = threadIdx.x;
  if (blockIdx.x == 0) {
    for (int i = t; i < 768; i += 256) protoAcc[i] = 0.f;
    if (t < 8) ceAcc[t] = 0.f;
    if (t == 0) { diag[0] = 0; syncCtr[0] = 0; syncCtr[1] = 0; }
  }
  if (t < 64) cnt[t >> 4][t & 15] = 0;
  __syncthreads();
  int n0 = blockIdx.x * 1024;
  int b = n0 >> 16;
  int hwt = (n0 & 65535) + 4 * t;
  uint2 mr = *(const uint2*)(msk + ((size_t)b << 16) + hwt);
  float m[4] = { lo16(mr.x), hi16(mr.x), lo16(mr.y), hi16(mr.y) };
  int cls[4] = {0, 0, 0, 0};
  bool v[4] = {false, false, false, false};
  #pragma unroll
  for (int s = 0; s < 8; s++) {
    uint2 lr = *(const uint2*)(lab + (((size_t)(b * 8 + s)) << 16) + hwt);
    float l[4] = { lo16(lr.x), hi16(lr.x), lo16(lr.y), hi16(lr.y) };
    #pragma unroll
    for (int j = 0; j < 4; j++) if (l[j] * m[j] > 0.f) { cls[j] = s; v[j] = true; }
  }
  int qtr = t >> 6;
  u32 fw = 0;
  #pragma unroll
  for (int j = 0; j < 4; j++) {
    bool h = false;
    if (v[j]) { float p = bfv(prb[(((size_t)(b * 8 + cls[j])) << 16) + hwt + j]); h = p < 0.97f; }
    int f = cls[j] | (v[j] ? 16 : 0) | (h ? 32 : 0);
    fw |= ((u32)f) << (8 * j);
    if (v[j]) atomicAdd(&cnt[qtr][cls[j]], 1);
    if (h)    atomicAdd(&cnt[qtr][8 + cls[j]], 1);
  }
  *(u32*)(flags + n0 + 4 * t) = fw;
  __syncthreads();
  if (t < 64) blockCnt[(t & 15) * NBLK + blockIdx.x * 4 + (t >> 4)] = cnt[t >> 4][t & 15];
}

// R8 k_pq body (proven) + block 512 = the exclusive scan (256-thread variant).
__global__ __launch_bounds__(256) void k_pq(const u16* __restrict__ mu, const u16* __restrict__ wgt,
                                            const u16* __restrict__ sig, u32* __restrict__ PQ,
                                            const int* __restrict__ blockCnt, int* __restrict__ blockOff,
                                            int* __restrict__ counts) {
  if (blockIdx.x == 512) {                       // folded scan: 4 waves x 4 counters
    int t = threadIdx.x;
    int w = t >> 6, lane = t & 63;
    for (int cc = 0; cc < 4; cc++) {
      int ctr = w * 4 + cc;
      int run = 0;
      for (int chk = 0; chk < 16; chk++) {
        int bidx = chk * 64 + lane;
        int v = blockCnt[ctr * NBLK + bidx];
        int x = v;
        for (int d = 1; d < 64; d <<= 1) { int tt = __shfl_up(x, d); if (lane >= d) x += tt; }
        blockOff[ctr * NBLK + bidx] = run + x - v;
        run += __shfl(x, 63);
      }
      if (lane == 0) counts[ctr] = run;   // [0..7]=count, [8..15]=hcount
    }
    return;
  }
  __shared__ u32 tile[256 * 33];
  int t = threadIdx.x;
  int n0 = blockIdx.x * 512;
  int b = n0 >> 16;
  int hwt = (n0 & 65535) + 2 * t;
  size_t cb = ((size_t)(b * 32)) << 16;
  u32 m2[32];
  float ss0 = 0.f, ss1 = 0.f;
  #pragma unroll
  for (int c = 0; c < 32; c++) {
    m2[c] = *(const u32*)(mu + cb + ((size_t)c << 16) + hwt);
    float a = lo16(m2[c]), d = hi16(m2[c]);
    ss0 += a * a; ss1 += d * d;
  }
  float rn0 = 1.0f / fmaxf(sqrtf(ss0), 1e-12f);
  float rn1 = 1.0f / fmaxf(sqrtf(ss1), 1e-12f);
  u32 pk0[32], pk1[32];
  #pragma unroll
  for (int c = 0; c < 32; c++) {
    u32 w2 = *(const u32*)(wgt + cb + ((size_t)c << 16) + hwt);
    u32 s2 = *(const u32*)(sig + cb + ((size_t)c << 16) + hwt);
    pk0[c] = packPQ(lo16(m2[c]) * rn0 * lo16(w2), lo16(s2) * lo16(w2));
    pk1[c] = packPQ(hi16(m2[c]) * rn1 * hi16(w2), hi16(s2) * hi16(w2));
  }
  #pragma unroll
  for (int ch = 0; ch < 2; ch++) {
    if ((t >> 7) == ch) {
      int l = t & 127;
      #pragma unroll
      for (int c = 0; c < 32; c++) {
        tile[(2 * l + 0) * 33 + c] = pk0[c];
        tile[(2 * l + 1) * 33 + c] = pk1[c];
      }
    }
    __syncthreads();
    uint4* dst = (uint4*)(PQ + (size_t)(n0 + ch * 256) * 32);
    for (int k = t; k < 2048; k += 256) {
      int p = k >> 3, c4 = (k & 7) * 4;
      dst[k] = make_uint4(tile[p * 33 + c4], tile[p * 33 + c4 + 1],
                          tile[p * 33 + c4 + 2], tile[p * 33 + c4 + 3]);
    }
    __syncthreads();
  }
}

// unchanged (proven)
__global__ __launch_bounds__(256) void k_place(const unsigned char* __restrict__ flags, const int* __restrict__ blockOff,
                                               int* __restrict__ tblV, int* __restrict__ tblH) {
  __shared__ int wcnt[4][16];
  int tid = threadIdx.x;
  int n = blockIdx.x * 256 + tid;
  int f = flags[n];
  int cls = f & 15; bool v = (f & 16) != 0, h = (f & 32) != 0;
  int wave = tid >> 6, lane = tid & 63;
  unsigned long long below = (1ull << lane) - 1ull;
  int rv = 0, rh = 0;
  for (int s = 0; s < 8; s++) {
    unsigned long long bv = __ballot(v && (cls == s));
    unsigned long long bh = __ballot(h && (cls == s));
    if (lane == 0) { wcnt[wave][s] = __popcll(bv); wcnt[wave][8 + s] = __popcll(bh); }
    if (cls == s) { rv = __popcll(bv & below); rh = __popcll(bh & below); }
  }
  __syncthreads();
  int preV = 0, preH = 0;
  for (int w2 = 0; w2 < wave; w2++) { preV += wcnt[w2][cls]; preH += wcnt[w2][8 + cls]; }
  if (v) tblV[(size_t)cls * NPIX + blockOff[cls * NBLK + blockIdx.x] + preV + rv] = n;
  if (h) tblH[(size_t)cls * NPIX + blockOff[(8 + cls) * NBLK + blockIdx.x] + preH + rh] = n;
}

// R9 k_proto body + last-block protoFinal fold.
__global__ __launch_bounds__(256) void k_proto(const u16* __restrict__ mu, const u16* __restrict__ wgt,
                                               const u16* __restrict__ sig, const int* __restrict__ tblV,
                                               const int* __restrict__ counts, float* __restrict__ protoAcc,
                                               u32* __restrict__ protoPQ, float* __restrict__ simL,
                                               int* __restrict__ diag, int* __restrict__ syncCtr) {
  int ch = blockIdx.x & 7;
  int s  = (blockIdx.x >> 3) & 7;
  int c  = blockIdx.x >> 6;
  int sc = s * 32 + c;
  int cnt = counts[s];
  const int* row = tblV + (size_t)s * NPIX;
  float a0 = 0.f, a1 = 0.f, a2 = 0.f;
  int r = ch * 256 + threadIdx.x;
  for (; r + 6144 < cnt; r += 8192) {
    int p0 = row[r], p1 = row[r + 2048], p2 = row[r + 4096], p3 = row[r + 6144];
    size_t A0 = (((size_t)((p0 >> 16) * 32 + c)) << 16) + (p0 & 65535);
    size_t A1 = (((size_t)((p1 >> 16) * 32 + c)) << 16) + (p1 & 65535);
    size_t A2 = (((size_t)((p2 >> 16) * 32 + c)) << 16) + (p2 & 65535);
    size_t A3 = (((size_t)((p3 >> 16) * 32 + c)) << 16) + (p3 & 65535);
    float m0 = bfv(mu[A0]), w0 = bfv(wgt[A0]), s0 = bfv(sig[A0]);
    float m1 = bfv(mu[A1]), w1 = bfv(wgt[A1]), s1 = bfv(sig[A1]);
    float m2_ = bfv(mu[A2]), w2 = bfv(wgt[A2]), s2 = bfv(sig[A2]);
    float m3 = bfv(mu[A3]), w3 = bfv(wgt[A3]), s3 = bfv(sig[A3]);
    float i0 = w0 / s0, i1 = w1 / s1, i2 = w2 / s2, i3 = w3 / s3;
    a0 += i0; a1 += i0 * m0; a2 += 1.0f / w0;
    a0 += i1; a1 += i1 * m1; a2 += 1.0f / w1;
    a0 += i2; a1 += i2 * m2_; a2 += 1.0f / w2;
    a0 += i3; a1 += i3 * m3; a2 += 1.0f / w3;
  }
  for (; r < cnt; r += 2048) {
    int pix = row[r];
    size_t a = (((size_t)((pix >> 16) * 32 + c)) << 16) + (pix & 65535);
    float mv = bfv(mu[a]), wv = bfv(wgt[a]), sv = bfv(sig[a]);
    float isw = wv / sv;
    a0 += isw; a1 += isw * mv; a2 += 1.0f / wv;
  }
  #pragma unroll
  for (int d = 1; d < 64; d <<= 1) {
    a0 += __shfl_xor(a0, d);
    a1 += __shfl_xor(a1, d);
    a2 += __shfl_xor(a2, d);
  }
  if ((threadIdx.x & 63) == 0) {
    atomicAdd(&protoAcc[sc * 3 + 0], a0);
    atomicAdd(&protoAcc[sc * 3 + 1], a1);
    atomicAdd(&protoAcc[sc * 3 + 2], a2);
  }
  // ---- last-block protoFinal ----
  __shared__ int sLast;
  __syncthreads();                                // drains this block's atomics
  if (threadIdx.x == 0) {
    __threadfence();
    sLast = (atomicAdd(&syncCtr[0], 1) == 2047) ? 1 : 0;
  }
  __syncthreads();
  if (!sLast) return;
  __shared__ float sP[256], sQ[256];
  __shared__ int alive;
  int tid = threadIdx.x;
  if (tid == 0) alive = 0;
  float b0 = aload(&protoAcc[tid * 3 + 0]);
  float b1 = aload(&protoAcc[tid * 3 + 1]);
  float b2 = aload(&protoAcc[tid * 3 + 2]);
  bool have = counts[tid >> 5] > 0;
  bool ok = (b0 > 0.f) && (b2 > 0.f);
  __syncthreads();
  if (have && !ok) atomicOr(diag, 2);
  if (have && ok) alive = 1;
  float psig = 1.0f / b0;
  float pmu  = psig * b1;
  float pw   = 1.0f / b2;
  float sq = (have && ok) ? pmu * pmu : 0.f;
  #pragma unroll
  for (int d = 1; d < 32; d <<= 1) sq += __shfl_xor(sq, d);
  float rn = 1.0f / fmaxf(sqrtf(sq), 1e-12f);
  float pP = (have && ok) ? pmu * rn * pw : 0.f;
  float pQ = (have && ok) ? psig * pw : 0.f;
  sP[tid] = pP; sQ[tid] = pQ;
  protoPQ[tid] = packPQ(pP, pQ);
  __syncthreads();
  if (tid == 0 && alive == 0) atomicOr(diag, 32);
  if (tid < 64) {
    int i = tid >> 3, j = tid & 7;
    if (j < 7) {
      int o = (i + 1 + j) & 7;
      float acc = 0.f;
      for (int cc = 0; cc < 32; cc++) {
        float d = sP[i * 32 + cc] - sP[o * 32 + cc];
        float dn = sQ[i * 32 + cc] + sQ[o * 32 + cc];
        acc += d * d / dn + logf(dn);
      }
      float sim = -0.5f * (acc * (1.0f / 32.0f));
      simL[i * 8 + j] = (counts[o] > 0) ? (sim * 2.0f) : -INFINITY;  // /TEMP(0.5)
    }
  }
}

// R9 k_sample + fast-math logit/gumbel + last-block final fold.
__global__ __launch_bounds__(256) void k_sample(TFKeys K, const float* __restrict__ simL,
                                                const int* __restrict__ counts,
                                                const int* __restrict__ tblV, const int* __restrict__ tblH,
                                                const u32* __restrict__ PQ, const u32* __restrict__ protoPQ,
                                                float* __restrict__ ceAcc, int* __restrict__ diag,
                                                int* __restrict__ syncCtr, u32* __restrict__ out) {
  __shared__ __align__(16) u32 sA[32];
  __shared__ float redM[4], redS[4];
  __shared__ int sAp;
  int blk = blockIdx.x;
  int i = blk >> 8, q = blk & 255;
  int t = threadIdx.x;
  if (t == 0) {                                  // anchor draw (bit-identical RNG)
    u32 bits = rbits(K.k1[i][0], K.k1[i][1], (u32)q);
    float u = u01(bits);
    int hc = counts[8 + i];
    int ra = (int)(u * (float)hc);
    int cap = hc - 1; if (cap < 0) cap = 0;
    if (ra > cap) ra = cap; if (ra < 0) ra = 0;
    int p = tblH[(size_t)i * NPIX + ra];
    if (p < 0) p = 0; if (p > NPIX - 1) p = NPIX - 1;
    sAp = p;
  }
  __syncthreads();
  if (t < 32) sA[t] = PQ[(size_t)sAp * 32 + t];
  u32 rem = (u32)(q * 256 + t);
  u32 k20 = K.k2[i][0], k21 = K.k2[i][1];
  float Lr[7];
  #pragma unroll
  for (int j = 0; j < 7; j++) Lr[j] = simL[i * 8 + j];
  float mg = 0.f; int pick = 0;
  #pragma unroll
  for (int j = 0; j < 7; j++) {
    u32 bits = rbits(k20, k21, rem * 7u + (u32)j);
    float f = u01(bits);
    float u = fmaxf(f, 1.17549435e-38f);
    float g = -__logf(-__logf(u));               // fast log: argmax-tie risk ~1e-6
    float v = g + Lr[j];
    if (j == 0) { mg = v; } else if (v > mg) { mg = v; pick = j; }
  }
  int nc = (i + 1 + pick) & 7;
  u32 bits3 = rbits(K.k3[i][0], K.k3[i][1], rem);
  float u3 = u01(bits3);
  int cntv = counts[nc];
  int rn = (int)(u3 * (float)cntv);
  int cap2 = cntv - 1; if (cap2 < 0) cap2 = 0;
  if (rn > cap2) rn = cap2; if (rn < 0) rn = 0;
  int np = tblV[(size_t)nc * NPIX + rn];
  if (np < 0) np = 0; if (np > NPIX - 1) np = NPIX - 1;
  __syncthreads();
  const uint4* A4 = (const uint4*)sA;
  const uint4* B  = (const uint4*)(PQ + (size_t)np * 32);
  float accD = 0.f, pr0 = 1.f, pr1 = 1.f;        // dn in [0.02,2.05]: prod16 safe in f32
  #pragma unroll
  for (int k = 0; k < 8; k++) {
    uint4 ua = A4[k], ub = B[k];
    float2 fa, fb; float d, dn;
    fa = unpackPQ(ua.x); fb = unpackPQ(ub.x); d = fa.x - fb.x; dn = fa.y + fb.y; accD += __fdividef(d * d, dn); if (k < 4) pr0 *= dn; else pr1 *= dn;
    fa = unpackPQ(ua.y); fb = unpackPQ(ub.y); d = fa.x - fb.x; dn = fa.y + fb.y; accD += __fdividef(d * d, dn); if (k < 4) pr0 *= dn; else pr1 *= dn;
    fa = unpackPQ(ua.z); fb = unpackPQ(ub.z); d = fa.x - fb.x; dn = fa.y + fb.y; accD += __fdividef(d * d, dn); if (k < 4) pr0 *= dn; else pr1 *= dn;
    fa = unpackPQ(ua.w); fb = unpackPQ(ub.w); d = fa.x - fb.x; dn = fa.y + fb.y; accD += __fdividef(d * d, dn); if (k < 4) pr0 *= dn; else pr1 *= dn;
  }
  float lN = -((accD + __logf(pr0) + __logf(pr1)) * (1.0f / 32.0f));
  float l0 = 0.f;
  if (t == 0) {                                  // positive (prototype) logit
    const uint4* B0 = (const uint4*)(protoPQ + i * 32);
    float aD = 0.f, p0_ = 1.f, p1_ = 1.f;
    #pragma unroll
    for (int k = 0; k < 8; k++) {
      uint4 ua = A4[k], ub = B0[k];
      float2 fa, fb; float d, dn;
      fa = unpackPQ(ua.x); fb = unpackPQ(ub.x); d = fa.x - fb.x; dn = fa.y + fb.y; aD += __fdividef(d * d, dn); if (k < 4) p0_ *= dn; else p1_ *= dn;
      fa = unpackPQ(ua.y); fb = unpackPQ(ub.y); d = fa.x - fb.x; dn = fa.y + fb.y; aD += __fdividef(d * d, dn); if (k < 4) p0_ *= dn; else p1_ *= dn;
      fa = unpackPQ(ua.z); fb = unpackPQ(ub.z); d = fa.x - fb.x; dn = fa.y + fb.y; aD += __fdividef(d * d, dn); if (k < 4) p0_ *= dn; else p1_ *= dn;
      fa = unpackPQ(ua.w); fb = unpackPQ(ub.w); d = fa.x - fb.x; dn = fa.y + fb.y; aD += __fdividef(d * d, dn); if (k < 4) p0_ *= dn; else p1_ *= dn;
    }
    l0 = -((aD + __logf(p0_) + __logf(p1_)) * (1.0f / 32.0f));
  }
  bool bad = !(lN == lN) || (t == 0 && !(l0 == l0));
  if (__ballot(bad) != 0ull && (t & 63) == 0) atomicOr(diag, 8);
  float lm = (t == 0) ? fmaxf(lN, l0) : lN;
  #pragma unroll
  for (int d = 1; d < 64; d <<= 1) lm = fmaxf(lm, __shfl_xor(lm, d));
  if ((t & 63) == 0) redM[t >> 6] = lm;
  __syncthreads();
  float M = fmaxf(fmaxf(redM[0], redM[1]), fmaxf(redM[2], redM[3]));
  float es = __expf(lN - M) + ((t == 0) ? __expf(l0 - M) : 0.f);
  #pragma unroll
  for (int d = 1; d < 64; d <<= 1) es += __shfl_xor(es, d);
  if ((t & 63) == 0) redS[t >> 6] = es;
  __syncthreads();
  if (t == 0) {
    float S = redS[0] + redS[1] + redS[2] + redS[3];
    float ce = (M + __logf(S)) - l0;
    atomicAdd(&ceAcc[i], ce);
  }
  // ---- last-block final ----
  __shared__ int sLast;
  __syncthreads();                               // drains ceAcc atomic
  if (t == 0) {
    __threadfence();
    sLast = (atomicAdd(&syncCtr[1], 1) == 2047) ? 1 : 0;
  }
  __syncthreads();
  if (sLast && t == 0) {
    float loss = 0.f; int vn = 0;
    int db = __hip_atomic_load(diag, __ATOMIC_RELAXED, __HIP_MEMORY_SCOPE_AGENT);
    for (int ii = 0; ii < 8; ii++) {
      if (counts[ii] > 0) vn++;
      float ce = aload(&ceAcc[ii]);
      if (counts[ii] > 0 && counts[8 + ii] > 0) {
        if (!(ce == ce)) db |= 4;
        loss += ce * (1.0f / 256.0f);
      }
    }
    if (vn == 0) db |= 1;
    loss = loss / (float)vn;
    if (!(loss == loss) && db == 0) db = 16;
    if (db != 0) loss = 4096.0f * (float)(1 + db);
    u32 fb = __float_as_uint(loss);
    u32 bv = (fb + 0x7FFFu + ((fb >> 16) & 1u)) >> 16;          // f32 -> bf16 RNE
    out[0] = (fb & 0xFFFF0000u) | (bv & 0xFFFFu);               // dual-decodable
  }
}

// ---------------------------------------------------------------------------
extern "C" void kernel_launch(void* const* d_in, const int* in_sizes, int n_in,
                              void* d_out, int out_size, void* d_ws, size_t ws_size,
                              hipStream_t stream) {
  (void)in_sizes; (void)n_in; (void)out_size; (void)ws_size;
  const u16* wgt = (const u16*)d_in[0];
  const u16* mu  = (const u16*)d_in[1];
  const u16* sig = (const u16*)d_in[2];
  const u16* lab = (const u16*)d_in[3];
  const u16* msk = (const u16*)d_in[4];
  const u16* prb = (const u16*)d_in[5];

  // workspace carve (256B-aligned); total ~49 MB
  char* wp = (char*)d_ws;
  auto take = [&](size_t bytes) -> void* { void* p = (void*)wp; wp += ((bytes + 255) & ~(size_t)255); return p; };
  u32*   PQ       = (u32*)  take((size_t)NPIX * 32 * 4);
  int*   tblV     = (int*)  take((size_t)NCLS * NPIX * 4);
  int*   tblH     = (int*)  take((size_t)NCLS * NPIX * 4);
  unsigned char* flags = (unsigned char*)take(NPIX);
  int*   blockCnt = (int*)  take(16 * NBLK * 4);
  int*   blockOff = (int*)  take(16 * NBLK * 4);
  float* protoAcc = (float*)take(768 * 4);
  u32*   protoPQ  = (u32*)  take(256 * 4);
  float* simL     = (float*)take(64 * 4);
  int*   counts   = (int*)  take(16 * 4);
  float* ceAcc    = (float*)take(8 * 4);
  int*   diag     = (int*)  take(4);
  int*   syncCtr  = (int*)  take(8);

  // Host-side JAX key derivation (partitionable/fold-like split)
  TFKeys K;
  for (u32 i = 0; i < 8; i++) {
    u32 ki0, ki1;
    tf2x32(0u, 42u, 0u, i, ki0, ki1);
    tf2x32(ki0, ki1, 0u, 0u, K.k1[i][0], K.k1[i][1]);
    tf2x32(ki0, ki1, 0u, 1u, K.k2[i][0], K.k2[i][1]);
    tf2x32(ki0, ki1, 0u, 2u, K.k3[i][0], K.k3[i][1]);
  }

  k_flags<<<256, 256, 0, stream>>>(lab, msk, prb, flags, blockCnt, protoAcc, ceAcc, diag, syncCtr);
  k_pq<<<513, 256, 0, stream>>>(mu, wgt, sig, PQ, blockCnt, blockOff, counts);
  k_place<<<1024, 256, 0, stream>>>(flags, blockOff, tblV, tblH);
  k_proto<<<2048, 256, 0, stream>>>(mu, wgt, sig, tblV, counts, protoAcc, protoPQ, simL, diag, syncCtr);
  k_sample<<<2048, 256, 0, stream>>>(K, simL, counts, tblV, tblH, PQ, protoPQ, ceAcc, diag, syncCtr, (u32*)d_out);
}